// Round 4
// baseline (158.806 us; speedup 1.0000x reference)
//
#include <hip/hip_runtime.h>
#include <math.h>

#define DEV __device__ __forceinline__

DEV float dot4(float4 a, float4 b){ return a.x*b.x + a.y*b.y + a.z*b.z + a.w*b.w; }

DEV float wave_sum(float v){
  #pragma unroll
  for (int off = 32; off; off >>= 1) v += __shfl_xor(v, off, 64);
  return v;
}

DEV float gelu_exact(float v){ return 0.5f * v * (1.f + erff(v * 0.70710678118654752f)); }

// K1: fused landmark-transpose + prob + zero(y1raw).
// Per (b,n) row: dist to 64 landmarks (lane=k), min-max norm, gaussian sim, row-normalize.
// lm is transpose-staged through LDS in 4 chunks of 48 float4-cols (48 KB LDS):
// LDS writes and reads are contiguous; the global side is 16B-scattered but lm (192 KB)
// is L2-resident after the first touch.
__global__ void __launch_bounds__(256) k_prob(const float* __restrict__ lm,
                                              const float* __restrict__ enc,
                                              float* __restrict__ prob,
                                              float* __restrict__ y1zero){
  int t = threadIdx.x, lane = t & 63, wv = t >> 6;
  int gid = blockIdx.x*256 + t;
  if (gid < 8000) y1zero[gid] = 0.f;          // blocks 0..31 zero the fc1 accumulator
  int row0 = blockIdx.x*8 + wv*2;
  __shared__ float4 ls[3072];                 // [col 0..47][k 0..63]
  const float4* L4 = (const float4*)lm;       // [64][192]
  const float4* X0 = (const float4*)(enc + (size_t)row0*768);
  const float4* X1 = X0 + 192;
  float dot0=0.f, dot1=0.f, xn0=0.f, xn1=0.f, ln=0.f;
  for (int c = 0; c < 4; ++c){
    if (c) __syncthreads();
    #pragma unroll
    for (int i = 0; i < 12; ++i){
      int idx = i*256 + t;
      int k = idx & 63, col = idx >> 6;
      ls[idx] = L4[k*192 + c*48 + col];       // contiguous LDS write, scattered L2 read
    }
    __syncthreads();
    #pragma unroll 8
    for (int hg = 0; hg < 48; ++hg){
      float4 l4 = ls[hg*64 + lane];           // contiguous across lanes: conflict-free
      float4 a = X0[c*48 + hg], b = X1[c*48 + hg];   // wave-uniform broadcast
      dot0 += dot4(a, l4); dot1 += dot4(b, l4);
      xn0  += dot4(a, a);  xn1  += dot4(b, b);
      ln   += dot4(l4, l4);                   // lane k's own landmark norm
    }
  }
  float d0 = sqrtf(fmaxf(xn0 + ln - 2.f*dot0, 0.f));
  float d1 = sqrtf(fmaxf(xn1 + ln - 2.f*dot1, 0.f));
  float mn0=d0, mx0=d0, mn1=d1, mx1=d1;
  #pragma unroll
  for (int off = 32; off; off >>= 1){
    mn0 = fminf(mn0, __shfl_xor(mn0, off, 64));
    mx0 = fmaxf(mx0, __shfl_xor(mx0, off, 64));
    mn1 = fminf(mn1, __shfl_xor(mn1, off, 64));
    mx1 = fmaxf(mx1, __shfl_xor(mx1, off, 64));
  }
  float nd0 = (d0 - mn0) / (mx0 - mn0 + 1e-6f);
  float nd1 = (d1 - mn1) / (mx1 - mn1 + 1e-6f);
  float s0 = expf(nd0*nd0 * (-1.f/0.18f));    // 2*d^2 = 2*0.3^2 = 0.18
  float s1 = expf(nd1*nd1 * (-1.f/0.18f));
  float sum0 = wave_sum(s0), sum1 = wave_sum(s1);
  prob[(size_t)row0*64 + lane]     = s0 / sum0;
  prob[(size_t)(row0+1)*64 + lane] = s1 / sum1;
}

// K2: out[b,k,h] = sum_n prob[b,n,k]*enc[b,n,h]; also mbar[b,h] = mean_k out[b,k,h].
__global__ void k_pool(const float* __restrict__ enc, const float* __restrict__ prob,
                       float* __restrict__ outp, float* __restrict__ mbar){
  int b = blockIdx.x / 48, ch = blockIdx.x % 48;
  int lane = threadIdx.x & 63, wv = threadIdx.x >> 6;
  int h0 = ch*16 + wv*4;
  const float* E = enc + (size_t)b*256*768 + h0;
  const float* P = prob + (size_t)b*256*64;
  float acc[4] = {0,0,0,0};
  #pragma unroll 4
  for (int n = 0; n < 256; ++n){
    float p = P[n*64 + lane];                              // coalesced
    float4 e0 = *(const float4*)(E + (size_t)n*768);       // broadcast
    acc[0] += p*e0.x; acc[1] += p*e0.y; acc[2] += p*e0.z; acc[3] += p*e0.w;
  }
  float* O = outp + ((size_t)b*64 + lane)*768 + h0;
  *(float4*)O = make_float4(acc[0],acc[1],acc[2],acc[3]);
  #pragma unroll
  for (int j = 0; j < 4; ++j){
    float v = wave_sum(acc[j]);
    if (lane == 0) mbar[(size_t)b*768 + h0 + j] = v * (1.f/64.f);
  }
}

// K3/4/5: o[b,j] = bias[j] + sum_i in[b,i]*W[j,i]; in is [8][768], one wave per j.
__global__ void k_vm768(const float* __restrict__ in, const float* __restrict__ W,
                        const float* __restrict__ bias, float* __restrict__ out){
  int lane = threadIdx.x & 63, wv = threadIdx.x >> 6;
  int j = blockIdx.x*4 + wv;
  const float4* Wr = (const float4*)(W + (size_t)j*768);
  const float4* IN = (const float4*)in;
  float acc[8] = {0,0,0,0,0,0,0,0};
  #pragma unroll
  for (int s = 0; s < 3; ++s){
    int ig = s*64 + lane;
    float4 w4 = Wr[ig];
    #pragma unroll
    for (int b = 0; b < 8; ++b) acc[b] += dot4(w4, IN[b*192 + ig]);
  }
  #pragma unroll
  for (int b = 0; b < 8; ++b){
    float v = wave_sum(acc[b]);
    if (lane == 0) out[b*768 + j] = v + bias[j];
  }
}

// K6: fc1 with fused xcat + atomic accumulation into y1raw.
// Grid = 64 kc-chunks (major) x 125 j-groups = 8000 blocks; LDS 24.8 KB -> 6 blocks/CU.
// Block: 8 j-rows x 768-float K-chunk. X chunk built on the fly as 2*outp + hx3
// and staged to LDS; each wave streams 2 W rows (6 x 16B loads issued before the
// staging barrier). W streams 196.6 MB of HBM exactly once.
__global__ void __launch_bounds__(256) k_fc1s(const float* __restrict__ outp,
                                              const float* __restrict__ hx3,
                                              const float* __restrict__ W,
                                              float* __restrict__ y1){
  int t = threadIdx.x, lane = t & 63, wv = t >> 6;
  int kc = blockIdx.x / 125, jg = blockIdx.x % 125;
  int j0 = jg*8;
  const float4* O4 = (const float4*)outp + kc*192;   // [b][12288] float4
  const float4* H4 = (const float4*)hx3;             // [b][192]
  const float4* Wa = (const float4*)W + (size_t)(j0 + wv*2)*12288 + kc*192;
  const float4* Wb = Wa + 12288;
  __shared__ float4 xs4[1536];   // [b][192]
  __shared__ float sp[64];

  // 1) issue the 6 W loads first — outstanding across the staging phase
  float4 wa[3], wb[3];
  #pragma unroll
  for (int s = 0; s < 3; ++s){ wa[s] = Wa[s*64 + lane]; wb[s] = Wb[s*64 + lane]; }

  // 2) stage X chunk = 2*outp + hx3 (fused xcat), 1536 float4, coalesced
  #pragma unroll
  for (int i = 0; i < 6; ++i){
    int idx = i*256 + t;
    int b = idx / 192, r = idx - b*192;              // (kc*192+r) % 192 == r
    float4 o = O4[(size_t)b*12288 + r];
    float4 g = H4[b*192 + r];
    float4 v;
    v.x = 2.f*o.x + g.x; v.y = 2.f*o.y + g.y; v.z = 2.f*o.z + g.z; v.w = 2.f*o.w + g.w;
    xs4[idx] = v;
  }
  __syncthreads();

  // 3) compute: 3 K-steps x 8 batches from LDS
  float acc0[8] = {0,0,0,0,0,0,0,0};
  float acc1[8] = {0,0,0,0,0,0,0,0};
  #pragma unroll
  for (int s = 0; s < 3; ++s){
    int ig = s*64 + lane;
    #pragma unroll
    for (int b = 0; b < 8; ++b){
      float4 xv = xs4[b*192 + ig];
      acc0[b] += dot4(wa[s], xv);
      acc1[b] += dot4(wb[s], xv);
    }
  }

  // 4) wave-reduce, stash, one atomicAdd per (j,b)
  #pragma unroll
  for (int b = 0; b < 8; ++b){
    float v0 = wave_sum(acc0[b]);
    float v1 = wave_sum(acc1[b]);
    if (lane == 0){ sp[(wv*2+0)*8 + b] = v0; sp[(wv*2+1)*8 + b] = v1; }
  }
  __syncthreads();
  if (t < 64){
    int jp = t >> 3, b = t & 7;
    atomicAdd(&y1[b*1000 + j0 + jp], sp[t]);
  }
}

// K7: fused bias+gelu -> fc2+gelu -> fc3. One block per batch b.
__global__ void __launch_bounds__(256) k_tail(const float* __restrict__ y1,
                                              const float* __restrict__ fb1,
                                              const float* __restrict__ W2,
                                              const float* __restrict__ fb2,
                                              const float* __restrict__ W3,
                                              const float* __restrict__ fb3,
                                              float* __restrict__ out){
  int b = blockIdx.x, t = threadIdx.x, lane = t & 63, wv = t >> 6;
  __shared__ __align__(16) float x1s[1000];
  __shared__ float x2s[100];
  #pragma unroll
  for (int i = 0; i < 4; ++i){
    int j = i*256 + t;
    if (j < 1000) x1s[j] = gelu_exact(y1[b*1000 + j] + fb1[j]);
  }
  __syncthreads();
  const float4* X4 = (const float4*)x1s;     // 250 float4
  for (int i = 0; i < 25; ++i){
    int m = wv*25 + i;
    const float4* Wr = (const float4*)(W2 + (size_t)m*1000);
    float acc = 0.f;
    #pragma unroll
    for (int s = 0; s < 4; ++s){
      int jg = s*64 + lane;
      if (jg < 250) acc += dot4(Wr[jg], X4[jg]);
    }
    acc = wave_sum(acc);
    if (lane == 0) x2s[m] = gelu_exact(acc + fb2[m]);
  }
  __syncthreads();
  if (t < 10){
    float acc = fb3[t];
    const float* Wr = W3 + t*100;
    #pragma unroll 4
    for (int m = 0; m < 100; ++m) acc += x2s[m]*Wr[m];
    out[b*10 + t] = acc;
  }
}

extern "C" void kernel_launch(void* const* d_in, const int* in_sizes, int n_in,
                              void* d_out, int out_size, void* d_ws, size_t ws_size,
                              hipStream_t stream){
  const float* enc = (const float*)d_in[0];
  const float* lm  = (const float*)d_in[1];
  // d_in[2] = alpha: provably unused — G = P dw P^T is strictly positive for any
  // alpha (dw diagonal = 1), so A=(G!=0) is all-ones and An = J/64.
  const float* w1  = (const float*)d_in[3];
  const float* b1  = (const float*)d_in[4];
  const float* w2  = (const float*)d_in[5];
  const float* b2  = (const float*)d_in[6];
  const float* w3  = (const float*)d_in[7];
  const float* b3  = (const float*)d_in[8];
  const float* fw1 = (const float*)d_in[9];
  const float* fb1 = (const float*)d_in[10];
  const float* fw2 = (const float*)d_in[11];
  const float* fb2 = (const float*)d_in[12];
  const float* fw3 = (const float*)d_in[13];
  const float* fb3 = (const float*)d_in[14];

  float* ws    = (float*)d_ws;
  float* prob  = ws;               // 131072
  float* outp  = prob  + 131072;   // 393216
  float* mbar  = outp  + 393216;   // 6144
  float* hx1   = mbar  + 6144;     // 6144
  float* hx2   = hx1   + 6144;     // 6144
  float* hx3   = hx2   + 6144;     // 6144
  float* y1raw = hx3   + 6144;     // 8000
  float* out   = (float*)d_out;

  k_prob <<<256, 256, 0, stream>>>(lm, enc, prob, y1raw);
  k_pool <<<384, 256, 0, stream>>>(enc, prob, outp, mbar);
  k_vm768<<<192, 256, 0, stream>>>(mbar, w1, b1, hx1);
  k_vm768<<<192, 256, 0, stream>>>(hx1,  w2, b2, hx2);
  k_vm768<<<192, 256, 0, stream>>>(hx2,  w3, b3, hx3);
  k_fc1s <<<8000,256, 0, stream>>>(outp, hx3, fw1, y1raw);
  k_tail <<<8,   256, 0, stream>>>(y1raw, fb1, fw2, fb2, fw3, fb3, out);
}